// Round 5
// baseline (936.779 us; speedup 1.0000x reference)
//
#include <hip/hip_runtime.h>
#include <hip/hip_bf16.h>
#include <math.h>

#define C_DIM 1024
#define H_DIM 4096
#define E_NUM 8

typedef __bf16 bf16x8 __attribute__((ext_vector_type(8)));
typedef float f32x4 __attribute__((ext_vector_type(4)));

__device__ __forceinline__ unsigned short f2bf(float f) {
  union { float f; unsigned u; } v; v.f = f;
  unsigned r = v.u + 0x7FFFu + ((v.u >> 16) & 1u);   // round-to-nearest-even
  return (unsigned short)(r >> 16);
}

__device__ __forceinline__ void gload16(const short* g, short* l) {
  __builtin_amdgcn_global_load_lds(
      (const __attribute__((address_space(1))) unsigned int*)g,
      (__attribute__((address_space(3))) unsigned int*)l, 16, 0, 0);
}

// ---------------------------------------------------------------------------
// Router (validated rounds 1-4)
// ---------------------------------------------------------------------------
__global__ __launch_bounds__(256) void router_kernel(
    const float* __restrict__ x, const float* __restrict__ noise,
    const float* __restrict__ Wr, const float* __restrict__ Wn,
    int2* __restrict__ idx_out, float2* __restrict__ gate_out, int N)
{
  int t = blockIdx.x;
  int tid = threadIdx.x;
  const float* xrow = x + (size_t)t * C_DIM;
  float accR[E_NUM], accN[E_NUM];
#pragma unroll
  for (int e = 0; e < E_NUM; e++) { accR[e] = 0.f; accN[e] = 0.f; }
  for (int c = tid; c < C_DIM; c += 256) {
    float xv = xrow[c];
    const float* wr = Wr + (size_t)c * E_NUM;
    const float* wn = Wn + (size_t)c * E_NUM;
#pragma unroll
    for (int e = 0; e < E_NUM; e++) {
      accR[e] = fmaf(xv, wr[e], accR[e]);
      accN[e] = fmaf(xv, wn[e], accN[e]);
    }
  }
#pragma unroll
  for (int e = 0; e < E_NUM; e++) {
    for (int off = 32; off > 0; off >>= 1) {
      accR[e] += __shfl_down(accR[e], off, 64);
      accN[e] += __shfl_down(accN[e], off, 64);
    }
  }
  __shared__ float red[4][2 * E_NUM];
  int lane = tid & 63, wave = tid >> 6;
  if (lane == 0) {
#pragma unroll
    for (int e = 0; e < E_NUM; e++) { red[wave][e] = accR[e]; red[wave][E_NUM + e] = accN[e]; }
  }
  __syncthreads();
  if (tid == 0) {
    float ns[E_NUM];
#pragma unroll
    for (int e = 0; e < E_NUM; e++) {
      float lg = red[0][e] + red[1][e] + red[2][e] + red[3][e];
      float nl = red[0][E_NUM + e] + red[1][E_NUM + e] + red[2][E_NUM + e] + red[3][E_NUM + e];
      float sp = fmaxf(nl, 0.f) + log1pf(expf(-fabsf(nl)));
      ns[e] = lg + noise[(size_t)t * E_NUM + e] * sp;
    }
    int i1 = 0; float m1 = ns[0];
    int i2 = -1; float m2 = -INFINITY;
#pragma unroll
    for (int e = 1; e < E_NUM; e++) {
      float v = ns[e];
      if (v > m1) { m2 = m1; i2 = i1; m1 = v; i1 = e; }
      else if (v > m2) { m2 = v; i2 = e; }
    }
    float e2 = expf(m2 - m1);
    float s = 1.f + e2;
    gate_out[t] = make_float2(1.f / s, e2 / s);
    idx_out[t] = make_int2(i1, i2);
  }
}

// ---------------------------------------------------------------------------
// Capacity scan (validated) + per-expert kept count
// ---------------------------------------------------------------------------
__global__ __launch_bounds__(256) void scan_kernel(
    const int2* __restrict__ idx, const float2* __restrict__ gates,
    int* __restrict__ s2t, float* __restrict__ gslot, int* __restrict__ counts,
    int N, int cap)
{
  int e = blockIdx.x;
  int tid = threadIdx.x;
  for (int s = tid; s < cap; s += 256) { s2t[(size_t)e * cap + s] = N; gslot[(size_t)e * cap + s] = 0.f; }
  __syncthreads();
  __shared__ int wtot[4];
  int lane = tid & 63, wave = tid >> 6;
  int running = 0;
  for (int base = 0; base < N; base += 256) {
    int t = base + tid;
    int2 ix = idx[t];
    bool flag = (ix.x == e) || (ix.y == e);
    unsigned long long m = __ballot(flag);
    int rank = __popcll(m & ((1ull << lane) - 1ull));
    if (lane == 0) wtot[wave] = __popcll(m);
    __syncthreads();
    int woff = 0;
    for (int w = 0; w < wave; w++) woff += wtot[w];
    int slot = running + woff + rank;
    if (flag && slot < cap) {
      s2t[(size_t)e * cap + slot] = t;
      gslot[(size_t)e * cap + slot] = (ix.x == e) ? gates[t].x : gates[t].y;
    }
    running += wtot[0] + wtot[1] + wtot[2] + wtot[3];
    __syncthreads();
  }
  if (tid == 0) counts[e] = min(running, cap);
}

// ---------------------------------------------------------------------------
// f32 -> bf16, 8 elems/thread (validated)
// ---------------------------------------------------------------------------
__global__ __launch_bounds__(256) void convert_x_kernel(
    const float* __restrict__ src, short* __restrict__ dst, int n8)
{
  int i = blockIdx.x * 256 + threadIdx.x;
  if (i >= n8) return;
  const float4* s = (const float4*)src + (size_t)i * 2;
  float4 a = s[0], b = s[1];
  union { unsigned short us[8]; uint4 v; } o;
  o.us[0] = f2bf(a.x); o.us[1] = f2bf(a.y); o.us[2] = f2bf(a.z); o.us[3] = f2bf(a.w);
  o.us[4] = f2bf(b.x); o.us[5] = f2bf(b.y); o.us[6] = f2bf(b.z); o.us[7] = f2bf(b.w);
  ((uint4*)dst)[i] = o.v;
}

// ---------------------------------------------------------------------------
// f32 [R][Cc] -> bf16 [Cc][R]  (validated)
// ---------------------------------------------------------------------------
__global__ __launch_bounds__(256) void transpose_convert_kernel(
    const float* __restrict__ src, short* __restrict__ dst,
    int R, int Cc)
{
  src += (size_t)blockIdx.z * R * Cc;
  dst += (size_t)blockIdx.z * (size_t)R * Cc;
  __shared__ float tile[64][65];
  int c0 = blockIdx.x * 64, r0 = blockIdx.y * 64;
  int tid = threadIdx.x;
  int tr = tid >> 4, tc = (tid & 15) * 4;
#pragma unroll
  for (int p = 0; p < 4; p++) {
    int r = p * 16 + tr;
    float4 v = *(const float4*)(src + (size_t)(r0 + r) * Cc + c0 + tc);
    tile[r][tc] = v.x; tile[r][tc + 1] = v.y; tile[r][tc + 2] = v.z; tile[r][tc + 3] = v.w;
  }
  __syncthreads();
#pragma unroll
  for (int p = 0; p < 4; p++) {
    int c = p * 16 + tr;
    union { unsigned short us[4]; ushort4 v; } o;
#pragma unroll
    for (int j = 0; j < 4; j++) o.us[j] = f2bf(tile[tc + j][c]);
    *(ushort4*)(dst + (size_t)(c0 + c) * R + r0 + tc) = o.v;
  }
}

// ---------------------------------------------------------------------------
// Simple-core MFMA GEMM (m97/m99 structure): 128x128 tile, BK=64, 256 thr
// (4 waves, 2x2, per-wave 64x64, acc[4][4]). Double-buffered LDS 2x(16+16) KB
// = 64 KB -> 2 blocks/CU. ONE __syncthreads per K-step; within a step:
// read 16 frags -> issue 8 global_load_lds for step i+1 into buf^1 -> 32 MFMA.
// The compiler's vmcnt(0)+lgkmcnt(0) at the barrier is exactly the needed
// wait; the MFMA phase + 2-block TLP cover the load latency.
// LDS layout per buffer: [kb=8][row=128][8] bf16 (lane-linear staging,
// 0-conflict b128 frag reads -- validated rounds 2-4).
// MODE 0 (mlp1): A = xbf via s2t gather, B = W1t [H][C]; silu -> bf16 h.
// MODE 1 (mlp2): A = h [cap][H], B = W2t [C][H]; gate * atomicAdd -> out.
// ---------------------------------------------------------------------------
template<int MODE>
__global__ __launch_bounds__(256, 2) void gemm_moe(
    const short* __restrict__ Abase, const short* __restrict__ Wt,
    const int* __restrict__ s2t, const float* __restrict__ gslot,
    const int* __restrict__ counts, void* __restrict__ outp,
    int cap, int N)
{
  __shared__ short As[2][8192];   // [buf][kb*1024 + row*8]
  __shared__ short Bs[2][8192];

  int e = blockIdx.z;
  int cnt = counts[e];
  int row0 = blockIdx.y * 128;
  if (row0 >= cnt) return;        // whole block is pad slots
  int col0 = blockIdx.x * 128;

  int tid = threadIdx.x;
  int w = tid >> 6, l = tid & 63;
  int wr = w >> 1, wc = w & 1;
  int rowT = tid & 127, kbT = tid >> 7;   // staging: row + kb-parity

  constexpr int KS = (MODE == 0) ? C_DIM : H_DIM;
  constexpr int NS = KS / 64;

  const short *pA, *pB;
  if (MODE == 0) {
    int tok = min(s2t[e * cap + row0 + rowT], N - 1);  // pad: harmless gather
    pA = Abase + (size_t)tok * C_DIM;
    pB = Wt + (size_t)e * (C_DIM * H_DIM) + (size_t)(col0 + rowT) * C_DIM;
  } else {
    pA = Abase + ((size_t)e * cap + row0 + rowT) * H_DIM;
    pB = Wt + (size_t)e * (C_DIM * H_DIM) + (size_t)(col0 + rowT) * H_DIM;
  }

  // frag read bases (shorts): [kb = kk*4 + (l>>4)][row = w*64 + m*16 + (l&15)]
  int aBase = (l >> 4) * 1024 + (wr * 64 + (l & 15)) * 8;
  int bBase = (l >> 4) * 1024 + (wc * 64 + (l & 15)) * 8;

  f32x4 acc[4][4];
#pragma unroll
  for (int m = 0; m < 4; m++)
#pragma unroll
    for (int n = 0; n < 4; n++) acc[m][n] = 0.f;

#define STAGE(k0, buf) { \
  _Pragma("unroll") for (int j = 0; j < 4; ++j) { \
    int kb = kbT + 2 * j; \
    gload16(pA + (k0) + kb * 8, &As[buf][kb * 1024 + rowT * 8]); \
    gload16(pB + (k0) + kb * 8, &Bs[buf][kb * 1024 + rowT * 8]); \
  } }

  STAGE(0, 0);
  int cur = 0;
#pragma unroll 1
  for (int i = 0; i < NS; ++i) {
    __syncthreads();              // compiler adds vmcnt(0): buf[cur] ready
    // 1) read all fragments of this step into registers
    bf16x8 af[4][2], bg[4][2];
#pragma unroll
    for (int m = 0; m < 4; m++)
#pragma unroll
      for (int kk = 0; kk < 2; kk++)
        af[m][kk] = *(const bf16x8*)&As[cur][aBase + m * 128 + kk * 4096];
#pragma unroll
    for (int n = 0; n < 4; n++)
#pragma unroll
      for (int kk = 0; kk < 2; kk++)
        bg[n][kk] = *(const bf16x8*)&Bs[cur][bBase + n * 128 + kk * 4096];
    // 2) issue next-step staging into the other buffer
    if (i + 1 < NS) STAGE((i + 1) * 64, cur ^ 1);
    // 3) compute (register-only; overlaps the in-flight loads)
#pragma unroll
    for (int m = 0; m < 4; m++)
#pragma unroll
      for (int n = 0; n < 4; n++) {
        acc[m][n] = __builtin_amdgcn_mfma_f32_16x16x32_bf16(af[m][0], bg[n][0], acc[m][n], 0, 0, 0);
        acc[m][n] = __builtin_amdgcn_mfma_f32_16x16x32_bf16(af[m][1], bg[n][1], acc[m][n], 0, 0, 0);
      }
    cur ^= 1;
  }
#undef STAGE

  // ---- epilogue (validated round-2 mapping) ----
  int orow = row0 + wr * 64 + (l >> 4) * 4;
  int ocol = col0 + wc * 64 + (l & 15);
  if (MODE == 0) {
    short* hE = (short*)outp + (size_t)e * cap * H_DIM;
#pragma unroll
    for (int m = 0; m < 4; m++)
#pragma unroll
      for (int r = 0; r < 4; r++) {
        size_t rb = (size_t)(orow + m * 16 + r) * H_DIM + ocol;
#pragma unroll
        for (int n = 0; n < 4; n++) {
          float v = acc[m][n][r];
          hE[rb + n * 16] = (short)f2bf(v / (1.f + expf(-v)));
        }
      }
  } else {
    float* out = (float*)outp;
#pragma unroll
    for (int m = 0; m < 4; m++)
#pragma unroll
      for (int r = 0; r < 4; r++) {
        int slot = row0 + wr * 64 + m * 16 + (l >> 4) * 4 + r;
        int tok = s2t[e * cap + slot];
        if (tok < N) {
          float g = gslot[e * cap + slot];
          float* op = out + (size_t)tok * C_DIM + ocol;
#pragma unroll
          for (int n = 0; n < 4; n++)
            atomicAdd(op + n * 16, g * acc[m][n][r]);
        }
      }
  }
}

extern "C" void kernel_launch(void* const* d_in, const int* in_sizes, int n_in,
                              void* d_out, int out_size, void* d_ws, size_t ws_size,
                              hipStream_t stream)
{
  const float* x     = (const float*)d_in[0];
  const float* noise = (const float*)d_in[1];
  const float* Wr    = (const float*)d_in[2];
  const float* Wn    = (const float*)d_in[3];
  const float* W1    = (const float*)d_in[4];
  const float* W2    = (const float*)d_in[5];
  float* out = (float*)d_out;

  int N = in_sizes[0] / C_DIM;                        // 8192
  int cap = (int)((double)N * 2.0 / E_NUM * 1.25);    // 2560
  int rows = cap / 128;                               // 20

  size_t off = 0;
  auto alloc = [&](size_t bytes) -> char* {
    char* r = (char*)d_ws + off;
    off += (bytes + 255) & ~(size_t)255;
    return r;
  };
  int2*   idx    = (int2*)alloc((size_t)N * sizeof(int2));
  float2* gates  = (float2*)alloc((size_t)N * sizeof(float2));
  int*    s2t    = (int*)alloc((size_t)E_NUM * cap * sizeof(int));
  float*  gslot  = (float*)alloc((size_t)E_NUM * cap * sizeof(float));
  int*    counts = (int*)alloc(E_NUM * sizeof(int));
  short*  xbf    = (short*)alloc((size_t)N * C_DIM * sizeof(short));
  short*  W1t    = (short*)alloc((size_t)E_NUM * C_DIM * H_DIM * sizeof(short));
  short*  W2t    = (short*)alloc((size_t)E_NUM * C_DIM * H_DIM * sizeof(short));
  short*  h      = (short*)alloc((size_t)E_NUM * cap * H_DIM * sizeof(short));
  (void)ws_size;

  hipMemsetAsync(d_out, 0, (size_t)out_size * sizeof(float), stream);
  router_kernel<<<N, 256, 0, stream>>>(x, noise, Wr, Wn, idx, gates, N);
  scan_kernel<<<E_NUM, 256, 0, stream>>>(idx, gates, s2t, gslot, counts, N, cap);
  convert_x_kernel<<<(N * C_DIM / 8 + 255) / 256, 256, 0, stream>>>(x, xbf, N * C_DIM / 8);
  transpose_convert_kernel<<<dim3(H_DIM / 64, C_DIM / 64, E_NUM), 256, 0, stream>>>(
      W1, W1t, C_DIM, H_DIM);
  transpose_convert_kernel<<<dim3(C_DIM / 64, H_DIM / 64, E_NUM), 256, 0, stream>>>(
      W2, W2t, H_DIM, C_DIM);

  // col innermost: col-siblings of a row-panel run temporally adjacent (L2/L3 reuse)
  gemm_moe<0><<<dim3(H_DIM / 128, rows, E_NUM), 256, 0, stream>>>(
      xbf, W1t, s2t, gslot, counts, h, cap, N);
  gemm_moe<1><<<dim3(C_DIM / 128, rows, E_NUM), 256, 0, stream>>>(
      h, W2t, s2t, gslot, counts, out, cap, N);
}